// Round 3
// baseline (2126.818 us; speedup 1.0000x reference)
//
#include <hip/hip_runtime.h>

#define NUM_CN   25000
#define NUM_VN   50000
#define NUM_E    200000
#define D_EMBED  16
#define D_HIDDEN 32
#define D_MSG    16
#define BATCH    16

// ---------------------------------------------------------------------------
// Workspace layout (int units) — 54.41 MB total (proven available in R2-R4):
#define WS_IDS_X   0           // 200000  (stores FROM node ids, CSR order)
#define WS_IDS_Z   200000      // 200000
#define WS_OFF_X   400000      // 50001
#define WS_OFF_Z   450001      // 50001
#define WS_CNT_X   500002      // 50000
#define WS_CNT_Z   550002      // 50000
#define WS_CUR_X   600002      // 50000 -> bits_x after fill
#define WS_CUR_Z   650002      // 50000 -> bits_z after fill
#define WS_INCL_X  700002      // 51200
#define WS_INCL_Z  751202      // 51200
#define WS_PSUM    802402      // 128
#define WS_BASE    802530      // 128
#define WS_A1X     802816      // 6400000 ints = 25.6 MB bf16
#define WS_A1Z     7202816     // 6400000
#define SCAN_CHUNKS 49

__global__ __launch_bounds__(256) void hist_kernel(
    const int* __restrict__ ti_x, const int* __restrict__ ti_z,
    int* __restrict__ cnt_x, int* __restrict__ cnt_z)
{
    int e = blockIdx.x * 256 + threadIdx.x;
    if (e >= NUM_E) return;
    atomicAdd(&cnt_x[ti_x[e]], 1);
    atomicAdd(&cnt_z[ti_z[e]], 1);
}

__global__ __launch_bounds__(1024) void scan1_kernel(
    const int* __restrict__ cnt_x, const int* __restrict__ cnt_z,
    int* __restrict__ incl_x, int* __restrict__ incl_z,
    int* __restrict__ psum)
{
    __shared__ int s[1024];
    const int ch  = blockIdx.y;
    const int blk = blockIdx.x;
    const int t   = threadIdx.x;
    const int gid = blk * 1024 + t;
    const int* cnt  = ch ? cnt_z  : cnt_x;
    int*       incl = ch ? incl_z : incl_x;
    int v = (gid < NUM_VN) ? cnt[gid] : 0;
    s[t] = v;
    __syncthreads();
#pragma unroll
    for (int d = 1; d < 1024; d <<= 1) {
        int x = 0;
        if (t >= d) x = s[t - d];
        __syncthreads();
        if (t >= d) s[t] += x;
        __syncthreads();
    }
    incl[gid] = s[t];
    if (t == 1023) psum[ch * 64 + blk] = s[1023];
}

__global__ void scan2_kernel(const int* __restrict__ psum, int* __restrict__ base)
{
    int ch = threadIdx.x;
    if (ch >= 2) return;
    int run = 0;
    for (int i = 0; i < SCAN_CHUNKS; ++i) {
        base[ch * 64 + i] = run;
        run += psum[ch * 64 + i];
    }
}

__global__ __launch_bounds__(1024) void scan3_kernel(
    const int* __restrict__ cnt_x, const int* __restrict__ cnt_z,
    const int* __restrict__ incl_x, const int* __restrict__ incl_z,
    const int* __restrict__ base,
    int* __restrict__ off_x, int* __restrict__ off_z,
    int* __restrict__ cur_x, int* __restrict__ cur_z)
{
    const int ch  = blockIdx.y;
    const int blk = blockIdx.x;
    const int t   = threadIdx.x;
    const int i   = blk * 1024 + t;
    if (i >= NUM_VN) return;
    const int* cnt  = ch ? cnt_z  : cnt_x;
    const int* incl = ch ? incl_z : incl_x;
    int*       off  = ch ? off_z  : off_x;
    int*       cur  = ch ? cur_z  : cur_x;
    int bs = base[ch * 64 + blk];
    int iv = incl[i];
    off[i + 1] = bs + iv;
    cur[i]     = bs + iv - cnt[i];
    if (i == 0) off[0] = 0;
}

// fill: CSR slot stores the FROM node id directly.
__global__ __launch_bounds__(256) void fill_kernel(
    const int* __restrict__ ti_x, const int* __restrict__ ti_z,
    const int* __restrict__ fi_x, const int* __restrict__ fi_z,
    int* __restrict__ cur_x, int* __restrict__ cur_z,
    int* __restrict__ ids_x, int* __restrict__ ids_z)
{
    int e = blockIdx.x * 256 + threadIdx.x;
    if (e >= NUM_E) return;
    int px = atomicAdd(&cur_x[ti_x[e]], 1);
    ids_x[px] = fi_x[e];
    int pz = atomicAdd(&cur_z[ti_z[e]], 1);
    ids_z[pz] = fi_z[e];
}

// syn bitmask: bits[cn] bit b = syn[b,cn]. Runs AFTER fill (targets dead cur_*).
__global__ __launch_bounds__(256) void pack_bits_kernel(
    const int* __restrict__ syn_x, const int* __restrict__ syn_z,
    unsigned* __restrict__ bits_x, unsigned* __restrict__ bits_z)
{
    int cn = blockIdx.x * 256 + threadIdx.x;
    if (cn >= NUM_CN) return;
    unsigned wx = 0, wz = 0;
#pragma unroll
    for (int b = 0; b < BATCH; ++b) {
        wx |= (unsigned)(syn_x[b * NUM_CN + cn] & 1) << b;
        wz |= (unsigned)(syn_z[b * NUM_CN + cn] & 1) << b;
    }
    bits_x[cn] = wx;
    bits_z[cn] = wz;
}

// ---------------------------------------------------------------------------
__device__ __forceinline__ unsigned pack_bf16(float a, float b) {
    unsigned ua = __float_as_uint(a); ua += 0x7fff + ((ua >> 16) & 1);
    unsigned ub = __float_as_uint(b); ub += 0x7fff + ((ub >> 16) & 1);
    return (ua >> 16) | (ub & 0xffff0000u);
}

// a1[ch][cn][b][32] = h_from[b,cn,:] @ W1[0:16,:]  bf16 lane-interleaved.
// MASK FOLDED IN: if syn[b,cn]==0, the row is written as bf16 -inf, so the
// gather-side relu(a1 + a2) == 0 reproduces mask*relu(...) with no per-edge
// mask load or fmaf-by-mask.
__global__ __launch_bounds__(256) void a1_kernel(
    const float* __restrict__ h_from_x, const float* __restrict__ h_from_z,
    const float* __restrict__ Wx1, const float* __restrict__ Wz1,
    const unsigned* __restrict__ bits_x, const unsigned* __restrict__ bits_z,
    uint4* __restrict__ a1x, uint4* __restrict__ a1z)
{
    int t = blockIdx.x * 256 + threadIdx.x;
    if (t >= NUM_CN * BATCH) return;
    const int ch = blockIdx.y;
    const int b  = t & 15;
    const int cn = t >> 4;
    const float* hsrc = (ch ? h_from_z : h_from_x) + ((size_t)b * NUM_CN + cn) * D_EMBED;
    const float* W1   = ch ? Wz1 : Wx1;
    const unsigned mw = (ch ? bits_z : bits_x)[cn];
    const bool on = (mw >> b) & 1u;
    uint4* dst = (ch ? a1z : a1x) + (size_t)cn * 64;

    float hf[D_EMBED];
#pragma unroll
    for (int i = 0; i < 4; ++i) {
        float4 v = ((const float4*)hsrc)[i];
        hf[4 * i + 0] = v.x; hf[4 * i + 1] = v.y;
        hf[4 * i + 2] = v.z; hf[4 * i + 3] = v.w;
    }
    float a[D_HIDDEN];
#pragma unroll
    for (int j = 0; j < D_HIDDEN; ++j) a[j] = 0.0f;
#pragma unroll
    for (int i = 0; i < D_EMBED; ++i) {
        const float fi = hf[i];
#pragma unroll
        for (int j = 0; j < D_HIDDEN; ++j)
            a[j] = fmaf(fi, W1[i * D_HIDDEN + j], a[j]);
    }
    unsigned u[16];
#pragma unroll
    for (int j = 0; j < 16; ++j)
        u[j] = on ? pack_bf16(a[2 * j], a[2 * j + 1]) : 0xFF80FF80u;
#pragma unroll
    for (int p = 0; p < 4; ++p) {
        uint4 q;
        q.x = u[4 * p + 0]; q.y = u[4 * p + 1];
        q.z = u[4 * p + 2]; q.w = u[4 * p + 3];
        dst[p * 16 + b] = q;
    }
}

// ---------------------------------------------------------------------------
// QUARTER-SPLIT gather+node. Thread = (n, q, b): lane = q*16+b, wave = ONE
// node x 4 quarters x 16 batches. Quarter q owns hidden slice [8q, 8q+8).
//  - per-edge: ONE uint4 load per lane; wave load = 1024 contiguous bytes
//    (lane id == uint4 index within the node's a1 block) -> perfect coalesce
//  - zero intra-wave divergence (single node per wave)
//  - true liveness ~45 regs -> __launch_bounds__(256,8) caps 64 VGPR, no
//    spill, 8 waves/SIMD (R0/R1 showed the 64-VGPR tier is worth ~40%)
// Cross-quarter sums via __shfl_xor(16/32) butterflies.

// one channel: act = slice of ht@W1[16:32]; hacc = sum_e relu(a1'[e]+act);
// m_full[16] = butterfly(hacc @ W2-slice)  (full message in every lane)
__device__ __forceinline__ void channel_q(
    const float* __restrict__ ht, int n, int q, int lane,
    const int* __restrict__ off, const int* __restrict__ ids,
    const uint4* __restrict__ a1,
    const float* __restrict__ W1, const float* __restrict__ W2,
    float* __restrict__ mfull)
{
    float2 act[4];
#pragma unroll
    for (int p = 0; p < 4; ++p) { act[p].x = 0.0f; act[p].y = 0.0f; }
#pragma unroll
    for (int i = 0; i < D_EMBED; ++i) {
        const float hi = ht[i];
        const float* w = W1 + (D_EMBED + i) * D_HIDDEN + 8 * q;
#pragma unroll
        for (int p = 0; p < 4; ++p) {
            act[p].x = fmaf(hi, w[2 * p],     act[p].x);
            act[p].y = fmaf(hi, w[2 * p + 1], act[p].y);
        }
    }

    float2 hacc[4];
#pragma unroll
    for (int p = 0; p < 4; ++p) { hacc[p].x = 0.0f; hacc[p].y = 0.0f; }

    const uint4* a1L = a1 + lane;   // lane = q*16+b == uint4 index in block
    const int ks = off[n], ke = off[n + 1];
    int k = ks;
    for (; k + 1 < ke; k += 2) {
        const uint4 va = a1L[(size_t)ids[k]     * 64];
        const uint4 vb = a1L[(size_t)ids[k + 1] * 64];
        unsigned ua[4] = {va.x, va.y, va.z, va.w};
#pragma unroll
        for (int p = 0; p < 4; ++p) {
            float lo = __uint_as_float(ua[p] << 16);
            float hi = __uint_as_float(ua[p] & 0xffff0000u);
            hacc[p].x += fmaxf(act[p].x + lo, 0.0f);
            hacc[p].y += fmaxf(act[p].y + hi, 0.0f);
        }
        unsigned ub[4] = {vb.x, vb.y, vb.z, vb.w};
#pragma unroll
        for (int p = 0; p < 4; ++p) {
            float lo = __uint_as_float(ub[p] << 16);
            float hi = __uint_as_float(ub[p] & 0xffff0000u);
            hacc[p].x += fmaxf(act[p].x + lo, 0.0f);
            hacc[p].y += fmaxf(act[p].y + hi, 0.0f);
        }
    }
    if (k < ke) {
        const uint4 va = a1L[(size_t)ids[k] * 64];
        unsigned ua[4] = {va.x, va.y, va.z, va.w};
#pragma unroll
        for (int p = 0; p < 4; ++p) {
            float lo = __uint_as_float(ua[p] << 16);
            float hi = __uint_as_float(ua[p] & 0xffff0000u);
            hacc[p].x += fmaxf(act[p].x + lo, 0.0f);
            hacc[p].y += fmaxf(act[p].y + hi, 0.0f);
        }
    }

    // partial message over this quarter's 8 hidden
#pragma unroll
    for (int j = 0; j < D_MSG; ++j) mfull[j] = 0.0f;
#pragma unroll
    for (int p = 0; p < 4; ++p) {
        const float* w0 = W2 + (8 * q + 2 * p) * D_MSG;
        const float* w1 = w0 + D_MSG;
        const float h0 = hacc[p].x, h1 = hacc[p].y;
#pragma unroll
        for (int j = 0; j < D_MSG; ++j)
            mfull[j] = fmaf(h0, w0[j], fmaf(h1, w1[j], mfull[j]));
    }
    // butterfly across quarters (lanes ^16, ^32 share n,b) -> full m
#pragma unroll
    for (int j = 0; j < D_MSG; ++j) mfull[j] += __shfl_xor(mfull[j], 16, 64);
#pragma unroll
    for (int j = 0; j < D_MSG; ++j) mfull[j] += __shfl_xor(mfull[j], 32, 64);
}

__global__ __launch_bounds__(256, 8) void gather_node_kernel(
    const float* __restrict__ h_to,
    const int* __restrict__ off_x, const int* __restrict__ ids_x,
    const int* __restrict__ off_z, const int* __restrict__ ids_z,
    const uint4* __restrict__ a1x, const uint4* __restrict__ a1z,
    const float* __restrict__ Wx1, const float* __restrict__ Wx2,
    const float* __restrict__ Wz1, const float* __restrict__ Wz2,
    const float* __restrict__ We1, const float* __restrict__ We2,
    float* __restrict__ out)
{
    const int t    = blockIdx.x * 256 + threadIdx.x;   // grid exact: VN*64
    const int lane = t & 63;
    const int b    = lane & 15;
    const int q    = lane >> 4;
    const int n    = t >> 6;
    const size_t slot = (size_t)b * NUM_VN + n;
    const float* ht_slot = h_to + slot * D_EMBED;

    float ht[D_EMBED];
#pragma unroll
    for (int i = 0; i < 4; ++i) {
        float4 v = ((const float4*)ht_slot)[i];
        ht[4 * i + 0] = v.x; ht[4 * i + 1] = v.y;
        ht[4 * i + 2] = v.z; ht[4 * i + 3] = v.w;
    }

    // hid accumulator for this quarter's 8 hidden outputs of the node MLP
    float2 hid[4];
#pragma unroll
    for (int p = 0; p < 4; ++p) { hid[p].x = 0.0f; hid[p].y = 0.0f; }

    float m[D_MSG];

    // ---- channel X: consume m into hid immediately (m dies before z loop) --
    channel_q(ht, n, q, lane, off_x, ids_x, a1x, Wx1, Wx2, m);
#pragma unroll
    for (int i = 0; i < D_MSG; ++i) {
        const float fi = m[i];
        const float* w = We1 + i * D_HIDDEN + 8 * q;
#pragma unroll
        for (int p = 0; p < 4; ++p) {
            hid[p].x = fmaf(fi, w[2 * p],     hid[p].x);
            hid[p].y = fmaf(fi, w[2 * p + 1], hid[p].y);
        }
    }

    // ---- channel Z ----
    channel_q(ht, n, q, lane, off_z, ids_z, a1z, Wz1, Wz2, m);
#pragma unroll
    for (int i = 0; i < D_MSG; ++i) {
        const float fi = m[i];
        const float* w = We1 + (D_MSG + i) * D_HIDDEN + 8 * q;
#pragma unroll
        for (int p = 0; p < 4; ++p) {
            hid[p].x = fmaf(fi, w[2 * p],     hid[p].x);
            hid[p].y = fmaf(fi, w[2 * p + 1], hid[p].y);
        }
    }

    // ---- ht rows 32..47 (each lane adds the FULL ht part for its own slice;
    //      no butterfly afterward, so no double count) ----
#pragma unroll
    for (int i = 0; i < D_EMBED; ++i) {
        const float fi = ht[i];
        const float* w = We1 + (2 * D_MSG + i) * D_HIDDEN + 8 * q;
#pragma unroll
        for (int p = 0; p < 4; ++p) {
            hid[p].x = fmaf(fi, w[2 * p],     hid[p].x);
            hid[p].y = fmaf(fi, w[2 * p + 1], hid[p].y);
        }
    }
#pragma unroll
    for (int p = 0; p < 4; ++p) {
        hid[p].x = fmaxf(hid[p].x, 0.0f);
        hid[p].y = fmaxf(hid[p].y, 0.0f);
    }

    // ---- o partial over this quarter's 8 hidden, butterfly, write slice ----
    float o[D_EMBED];
#pragma unroll
    for (int kk = 0; kk < D_EMBED; ++kk) o[kk] = 0.0f;
#pragma unroll
    for (int p = 0; p < 4; ++p) {
        const float* w0 = We2 + (8 * q + 2 * p) * D_EMBED;
        const float* w1 = w0 + D_EMBED;
        const float h0 = hid[p].x, h1 = hid[p].y;
#pragma unroll
        for (int kk = 0; kk < D_EMBED; ++kk)
            o[kk] = fmaf(h0, w0[kk], fmaf(h1, w1[kk], o[kk]));
    }
#pragma unroll
    for (int kk = 0; kk < D_EMBED; ++kk) o[kk] += __shfl_xor(o[kk], 16, 64);
#pragma unroll
    for (int kk = 0; kk < D_EMBED; ++kk) o[kk] += __shfl_xor(o[kk], 32, 64);

    float4 v;
    v.x = o[4 * q + 0]; v.y = o[4 * q + 1];
    v.z = o[4 * q + 2]; v.w = o[4 * q + 3];
    ((float4*)(out + slot * D_EMBED))[q] = v;
}

// ---------------------------------------------------------------------------
extern "C" void kernel_launch(void* const* d_in, const int* in_sizes, int n_in,
                              void* d_out, int out_size, void* d_ws, size_t ws_size,
                              hipStream_t stream) {
    const float* h_from_x = (const float*)d_in[0];
    const float* h_from_z = (const float*)d_in[1];
    const float* h_to     = (const float*)d_in[2];
    const int*   syn_x    = (const int*)d_in[3];
    const int*   syn_z    = (const int*)d_in[4];
    const int*   fi_x     = (const int*)d_in[5];
    const int*   ti_x     = (const int*)d_in[6];
    const int*   fi_z     = (const int*)d_in[7];
    const int*   ti_z     = (const int*)d_in[8];
    const float* Wx1      = (const float*)d_in[9];
    const float* Wx2      = (const float*)d_in[10];
    const float* Wz1      = (const float*)d_in[11];
    const float* Wz2      = (const float*)d_in[12];
    const float* We1      = (const float*)d_in[13];
    const float* We2      = (const float*)d_in[14];

    int* ws = (int*)d_ws;
    int* ids_x  = ws + WS_IDS_X;
    int* ids_z  = ws + WS_IDS_Z;
    int* off_x  = ws + WS_OFF_X;
    int* off_z  = ws + WS_OFF_Z;
    int* cnt_x  = ws + WS_CNT_X;
    int* cnt_z  = ws + WS_CNT_Z;
    int* cur_x  = ws + WS_CUR_X;
    int* cur_z  = ws + WS_CUR_Z;
    int* incl_x = ws + WS_INCL_X;
    int* incl_z = ws + WS_INCL_Z;
    int* psum   = ws + WS_PSUM;
    int* base   = ws + WS_BASE;
    uint4* a1x  = (uint4*)(ws + WS_A1X);
    uint4* a1z  = (uint4*)(ws + WS_A1Z);

    // cur_* are dead after fill -> reuse as syndrome bitmasks
    unsigned* bits_x = (unsigned*)cur_x;
    unsigned* bits_z = (unsigned*)cur_z;

    hipMemsetAsync(cnt_x, 0, 2 * NUM_VN * sizeof(int), stream);

    hist_kernel<<<dim3((NUM_E + 255) / 256), dim3(256), 0, stream>>>(
        ti_x, ti_z, cnt_x, cnt_z);
    scan1_kernel<<<dim3(SCAN_CHUNKS, 2), dim3(1024), 0, stream>>>(
        cnt_x, cnt_z, incl_x, incl_z, psum);
    scan2_kernel<<<dim3(1), dim3(64), 0, stream>>>(psum, base);
    scan3_kernel<<<dim3(SCAN_CHUNKS, 2), dim3(1024), 0, stream>>>(
        cnt_x, cnt_z, incl_x, incl_z, base, off_x, off_z, cur_x, cur_z);
    fill_kernel<<<dim3((NUM_E + 255) / 256), dim3(256), 0, stream>>>(
        ti_x, ti_z, fi_x, fi_z, cur_x, cur_z, ids_x, ids_z);
    pack_bits_kernel<<<dim3((NUM_CN + 255) / 256), dim3(256), 0, stream>>>(
        syn_x, syn_z, bits_x, bits_z);

    a1_kernel<<<dim3((NUM_CN * BATCH + 255) / 256, 2), dim3(256), 0, stream>>>(
        h_from_x, h_from_z, Wx1, Wz1, bits_x, bits_z, a1x, a1z);

    gather_node_kernel<<<dim3((NUM_VN * BATCH * 4) / 256), dim3(256), 0, stream>>>(
        h_to, off_x, ids_x, off_z, ids_z, a1x, a1z,
        Wx1, Wx2, Wz1, Wz2, We1, We2, (float*)d_out);
}

// Round 4
// 1067.868 us; speedup vs baseline: 1.9916x; 1.9916x over previous
//
#include <hip/hip_runtime.h>

#define NUM_CN   25000
#define NUM_VN   50000
#define NUM_E    200000
#define D_EMBED  16
#define D_HIDDEN 32
#define D_MSG    16
#define BATCH    16

// ---------------------------------------------------------------------------
// Workspace layout (int units) — 54.41 MB total (proven available in R2-R4):
#define WS_IDS_X   0           // 200000  (stores FROM node ids, CSR order)
#define WS_IDS_Z   200000      // 200000
#define WS_OFF_X   400000      // 50001
#define WS_OFF_Z   450001      // 50001
#define WS_CNT_X   500002      // 50000
#define WS_CNT_Z   550002      // 50000
#define WS_CUR_X   600002      // 50000 -> bits_x after fill
#define WS_CUR_Z   650002      // 50000 -> bits_z after fill
#define WS_INCL_X  700002      // 51200
#define WS_INCL_Z  751202      // 51200
#define WS_PSUM    802402      // 128
#define WS_BASE    802530      // 128
#define WS_A1X     802816      // 6400000 ints = 25.6 MB bf16
#define WS_A1Z     7202816     // 6400000
#define SCAN_CHUNKS 49

__global__ __launch_bounds__(256) void hist_kernel(
    const int* __restrict__ ti_x, const int* __restrict__ ti_z,
    int* __restrict__ cnt_x, int* __restrict__ cnt_z)
{
    int e = blockIdx.x * 256 + threadIdx.x;
    if (e >= NUM_E) return;
    atomicAdd(&cnt_x[ti_x[e]], 1);
    atomicAdd(&cnt_z[ti_z[e]], 1);
}

__global__ __launch_bounds__(1024) void scan1_kernel(
    const int* __restrict__ cnt_x, const int* __restrict__ cnt_z,
    int* __restrict__ incl_x, int* __restrict__ incl_z,
    int* __restrict__ psum)
{
    __shared__ int s[1024];
    const int ch  = blockIdx.y;
    const int blk = blockIdx.x;
    const int t   = threadIdx.x;
    const int gid = blk * 1024 + t;
    const int* cnt  = ch ? cnt_z  : cnt_x;
    int*       incl = ch ? incl_z : incl_x;
    int v = (gid < NUM_VN) ? cnt[gid] : 0;
    s[t] = v;
    __syncthreads();
#pragma unroll
    for (int d = 1; d < 1024; d <<= 1) {
        int x = 0;
        if (t >= d) x = s[t - d];
        __syncthreads();
        if (t >= d) s[t] += x;
        __syncthreads();
    }
    incl[gid] = s[t];
    if (t == 1023) psum[ch * 64 + blk] = s[1023];
}

__global__ void scan2_kernel(const int* __restrict__ psum, int* __restrict__ base)
{
    int ch = threadIdx.x;
    if (ch >= 2) return;
    int run = 0;
    for (int i = 0; i < SCAN_CHUNKS; ++i) {
        base[ch * 64 + i] = run;
        run += psum[ch * 64 + i];
    }
}

__global__ __launch_bounds__(1024) void scan3_kernel(
    const int* __restrict__ cnt_x, const int* __restrict__ cnt_z,
    const int* __restrict__ incl_x, const int* __restrict__ incl_z,
    const int* __restrict__ base,
    int* __restrict__ off_x, int* __restrict__ off_z,
    int* __restrict__ cur_x, int* __restrict__ cur_z)
{
    const int ch  = blockIdx.y;
    const int blk = blockIdx.x;
    const int t   = threadIdx.x;
    const int i   = blk * 1024 + t;
    if (i >= NUM_VN) return;
    const int* cnt  = ch ? cnt_z  : cnt_x;
    const int* incl = ch ? incl_z : incl_x;
    int*       off  = ch ? off_z  : off_x;
    int*       cur  = ch ? cur_z  : cur_x;
    int bs = base[ch * 64 + blk];
    int iv = incl[i];
    off[i + 1] = bs + iv;
    cur[i]     = bs + iv - cnt[i];
    if (i == 0) off[0] = 0;
}

// fill: CSR slot stores the FROM node id directly.
__global__ __launch_bounds__(256) void fill_kernel(
    const int* __restrict__ ti_x, const int* __restrict__ ti_z,
    const int* __restrict__ fi_x, const int* __restrict__ fi_z,
    int* __restrict__ cur_x, int* __restrict__ cur_z,
    int* __restrict__ ids_x, int* __restrict__ ids_z)
{
    int e = blockIdx.x * 256 + threadIdx.x;
    if (e >= NUM_E) return;
    int px = atomicAdd(&cur_x[ti_x[e]], 1);
    ids_x[px] = fi_x[e];
    int pz = atomicAdd(&cur_z[ti_z[e]], 1);
    ids_z[pz] = fi_z[e];
}

// syn bitmask: bits[cn] bit b = syn[b,cn]. Runs AFTER fill (targets dead cur_*).
__global__ __launch_bounds__(256) void pack_bits_kernel(
    const int* __restrict__ syn_x, const int* __restrict__ syn_z,
    unsigned* __restrict__ bits_x, unsigned* __restrict__ bits_z)
{
    int cn = blockIdx.x * 256 + threadIdx.x;
    if (cn >= NUM_CN) return;
    unsigned wx = 0, wz = 0;
#pragma unroll
    for (int b = 0; b < BATCH; ++b) {
        wx |= (unsigned)(syn_x[b * NUM_CN + cn] & 1) << b;
        wz |= (unsigned)(syn_z[b * NUM_CN + cn] & 1) << b;
    }
    bits_x[cn] = wx;
    bits_z[cn] = wz;
}

// ---------------------------------------------------------------------------
__device__ __forceinline__ unsigned pack_bf16(float a, float b) {
    unsigned ua = __float_as_uint(a); ua += 0x7fff + ((ua >> 16) & 1);
    unsigned ub = __float_as_uint(b); ub += 0x7fff + ((ub >> 16) & 1);
    return (ua >> 16) | (ub & 0xffff0000u);
}

// a1[ch][cn][b][32] = h_from[b,cn,:] @ W1[0:16,:]  bf16 lane-interleaved:
// uint4 #(p*16+b) of a node's 64-uint4 block = hidden pairs [8p,8p+8) for
// batch b. MASK FOLDED IN: syn==0 rows are bf16 -inf so relu(a1+act)==0.
__global__ __launch_bounds__(256) void a1_kernel(
    const float* __restrict__ h_from_x, const float* __restrict__ h_from_z,
    const float* __restrict__ Wx1, const float* __restrict__ Wz1,
    const unsigned* __restrict__ bits_x, const unsigned* __restrict__ bits_z,
    uint4* __restrict__ a1x, uint4* __restrict__ a1z)
{
    int t = blockIdx.x * 256 + threadIdx.x;
    if (t >= NUM_CN * BATCH) return;
    const int ch = blockIdx.y;
    const int b  = t & 15;
    const int cn = t >> 4;
    const float* hsrc = (ch ? h_from_z : h_from_x) + ((size_t)b * NUM_CN + cn) * D_EMBED;
    const float* W1   = ch ? Wz1 : Wx1;
    const unsigned mw = (ch ? bits_z : bits_x)[cn];
    const bool on = (mw >> b) & 1u;
    uint4* dst = (ch ? a1z : a1x) + (size_t)cn * 64;

    float hf[D_EMBED];
#pragma unroll
    for (int i = 0; i < 4; ++i) {
        float4 v = ((const float4*)hsrc)[i];
        hf[4 * i + 0] = v.x; hf[4 * i + 1] = v.y;
        hf[4 * i + 2] = v.z; hf[4 * i + 3] = v.w;
    }
    float a[D_HIDDEN];
#pragma unroll
    for (int j = 0; j < D_HIDDEN; ++j) a[j] = 0.0f;
#pragma unroll
    for (int i = 0; i < D_EMBED; ++i) {
        const float fi = hf[i];
#pragma unroll
        for (int j = 0; j < D_HIDDEN; ++j)
            a[j] = fmaf(fi, W1[i * D_HIDDEN + j], a[j]);
    }
    unsigned u[16];
#pragma unroll
    for (int j = 0; j < 16; ++j)
        u[j] = on ? pack_bf16(a[2 * j], a[2 * j + 1]) : 0xFF80FF80u;
#pragma unroll
    for (int p = 0; p < 4; ++p) {
        uint4 q;
        q.x = u[4 * p + 0]; q.y = u[4 * p + 1];
        q.z = u[4 * p + 2]; q.w = u[4 * p + 3];
        dst[p * 16 + b] = q;
    }
}

// ---------------------------------------------------------------------------
// QUARTER-SPLIT fused gather+node, liveness-first redesign.
// Thread = (n, q, b), lane = b*4+q (q in lane bits 0-1 -> butterflies are
// shfl_xor 1,2). Wave = ONE node: zero trip-count divergence; each lane
// loads ONE uint4 per edge (wave = the node's full 1024 B block, perfectly
// coalesced).  Liveness discipline (R0/R2 lessons — latency-bound kernel,
// the <=64-VGPR / 8-wave tier is the target, but by CONSTRUCTION, not pin):
//  - act_x AND act_z computed up front, ht dropped, reloaded later (L1-hot)
//  - full m[16] lives only between butterfly and immediate We1-consume
//  - no dynamic register-array indexing anywhere (cndmask quarter select)
//  - NO __launch_bounds__ min-wave pin (R0: -46 reg forced spills; R2:
//    LDS-demotion + 5e9 B scratch). Plain (256).

// one channel: hacc = sum_e relu(a1'[e] + act); m = butterfly(hacc @ W2-rows)
__device__ __forceinline__ void channel_q(
    int n, int a1i, int q,
    const int* __restrict__ off, const int* __restrict__ ids,
    const uint4* __restrict__ a1,
    const float2* __restrict__ act, const float* __restrict__ W2,
    float* __restrict__ m)
{
    float2 hacc[4];
#pragma unroll
    for (int p = 0; p < 4; ++p) { hacc[p].x = 0.0f; hacc[p].y = 0.0f; }

    const int ks = off[n], ke = off[n + 1];
    int k = ks;
    for (; k + 1 < ke; k += 2) {
        const uint4 va = a1[(size_t)ids[k]     * 64 + a1i];
        const uint4 vb = a1[(size_t)ids[k + 1] * 64 + a1i];
        unsigned ua[4] = {va.x, va.y, va.z, va.w};
#pragma unroll
        for (int p = 0; p < 4; ++p) {
            float lo = __uint_as_float(ua[p] << 16);
            float hi = __uint_as_float(ua[p] & 0xffff0000u);
            hacc[p].x += fmaxf(act[p].x + lo, 0.0f);
            hacc[p].y += fmaxf(act[p].y + hi, 0.0f);
        }
        unsigned ub[4] = {vb.x, vb.y, vb.z, vb.w};
#pragma unroll
        for (int p = 0; p < 4; ++p) {
            float lo = __uint_as_float(ub[p] << 16);
            float hi = __uint_as_float(ub[p] & 0xffff0000u);
            hacc[p].x += fmaxf(act[p].x + lo, 0.0f);
            hacc[p].y += fmaxf(act[p].y + hi, 0.0f);
        }
    }
    if (k < ke) {
        const uint4 va = a1[(size_t)ids[k] * 64 + a1i];
        unsigned ua[4] = {va.x, va.y, va.z, va.w};
#pragma unroll
        for (int p = 0; p < 4; ++p) {
            float lo = __uint_as_float(ua[p] << 16);
            float hi = __uint_as_float(ua[p] & 0xffff0000u);
            hacc[p].x += fmaxf(act[p].x + lo, 0.0f);
            hacc[p].y += fmaxf(act[p].y + hi, 0.0f);
        }
    }

    // partial message over this quarter's 8 hidden rows, then butterfly to
    // full m across the 4 quarter-lanes (bits 0-1 of lane share (n,b))
#pragma unroll
    for (int j = 0; j < D_MSG; ++j) m[j] = 0.0f;
#pragma unroll
    for (int p = 0; p < 4; ++p) {
        const float* w0 = W2 + (8 * q + 2 * p) * D_MSG;
        const float* w1 = w0 + D_MSG;
        const float h0 = hacc[p].x, h1 = hacc[p].y;
#pragma unroll
        for (int j = 0; j < D_MSG; ++j)
            m[j] = fmaf(h0, w0[j], fmaf(h1, w1[j], m[j]));
    }
#pragma unroll
    for (int j = 0; j < D_MSG; ++j) m[j] += __shfl_xor(m[j], 1, 64);
#pragma unroll
    for (int j = 0; j < D_MSG; ++j) m[j] += __shfl_xor(m[j], 2, 64);
}

__global__ __launch_bounds__(256) void gather_node_kernel(
    const float* __restrict__ h_to,
    const int* __restrict__ off_x, const int* __restrict__ ids_x,
    const int* __restrict__ off_z, const int* __restrict__ ids_z,
    const uint4* __restrict__ a1x, const uint4* __restrict__ a1z,
    const float* __restrict__ Wx1, const float* __restrict__ Wx2,
    const float* __restrict__ Wz1, const float* __restrict__ Wz2,
    const float* __restrict__ We1, const float* __restrict__ We2,
    float* __restrict__ out)
{
    const int t    = blockIdx.x * 256 + threadIdx.x;   // grid exact: VN*64
    const int lane = t & 63;
    const int q    = lane & 3;
    const int b    = lane >> 2;
    const int n    = t >> 6;
    const int a1i  = q * 16 + b;       // uint4 index in a node's a1 block
    const size_t slot = (size_t)b * NUM_VN + n;
    const float* ht_slot = h_to + slot * D_EMBED;

    // ---- phase 1: both channel activations for this quarter; ht then dies
    float2 ax[4], az[4];
#pragma unroll
    for (int p = 0; p < 4; ++p) {
        ax[p].x = 0.0f; ax[p].y = 0.0f;
        az[p].x = 0.0f; az[p].y = 0.0f;
    }
#pragma unroll
    for (int i4 = 0; i4 < 4; ++i4) {
        float4 v = ((const float4*)ht_slot)[i4];
        float hv[4] = {v.x, v.y, v.z, v.w};
#pragma unroll
        for (int j = 0; j < 4; ++j) {
            const float fi = hv[j];
            const float* wx = Wx1 + (D_EMBED + 4 * i4 + j) * D_HIDDEN + 8 * q;
            const float* wz = Wz1 + (D_EMBED + 4 * i4 + j) * D_HIDDEN + 8 * q;
#pragma unroll
            for (int p = 0; p < 4; ++p) {
                ax[p].x = fmaf(fi, wx[2 * p],     ax[p].x);
                ax[p].y = fmaf(fi, wx[2 * p + 1], ax[p].y);
                az[p].x = fmaf(fi, wz[2 * p],     az[p].x);
                az[p].y = fmaf(fi, wz[2 * p + 1], az[p].y);
            }
        }
    }

    float2 hid[4];
#pragma unroll
    for (int p = 0; p < 4; ++p) { hid[p].x = 0.0f; hid[p].y = 0.0f; }

    {   // ---- channel X; m consumed into hid immediately, then dead
        float m[D_MSG];
        channel_q(n, a1i, q, off_x, ids_x, a1x, ax, Wx2, m);
#pragma unroll
        for (int i = 0; i < D_MSG; ++i) {
            const float fi = m[i];
            const float* w = We1 + i * D_HIDDEN + 8 * q;
#pragma unroll
            for (int p = 0; p < 4; ++p) {
                hid[p].x = fmaf(fi, w[2 * p],     hid[p].x);
                hid[p].y = fmaf(fi, w[2 * p + 1], hid[p].y);
            }
        }
    }
    {   // ---- channel Z
        float m[D_MSG];
        channel_q(n, a1i, q, off_z, ids_z, a1z, az, Wz2, m);
#pragma unroll
        for (int i = 0; i < D_MSG; ++i) {
            const float fi = m[i];
            const float* w = We1 + (D_MSG + i) * D_HIDDEN + 8 * q;
#pragma unroll
            for (int p = 0; p < 4; ++p) {
                hid[p].x = fmaf(fi, w[2 * p],     hid[p].x);
                hid[p].y = fmaf(fi, w[2 * p + 1], hid[p].y);
            }
        }
    }

    // ---- feat rows 32..47: reload ht (L1-hot), consume directly
#pragma unroll
    for (int i4 = 0; i4 < 4; ++i4) {
        float4 v = ((const float4*)ht_slot)[i4];
        float hv[4] = {v.x, v.y, v.z, v.w};
#pragma unroll
        for (int j = 0; j < 4; ++j) {
            const float fi = hv[j];
            const float* w = We1 + (2 * D_MSG + 4 * i4 + j) * D_HIDDEN + 8 * q;
#pragma unroll
            for (int p = 0; p < 4; ++p) {
                hid[p].x = fmaf(fi, w[2 * p],     hid[p].x);
                hid[p].y = fmaf(fi, w[2 * p + 1], hid[p].y);
            }
        }
    }
#pragma unroll
    for (int p = 0; p < 4; ++p) {
        hid[p].x = fmaxf(hid[p].x, 0.0f);
        hid[p].y = fmaxf(hid[p].y, 0.0f);
    }

    // ---- o partial over this quarter's 8 hidden, butterfly to full o
    float o[D_EMBED];
#pragma unroll
    for (int kk = 0; kk < D_EMBED; ++kk) o[kk] = 0.0f;
#pragma unroll
    for (int p = 0; p < 4; ++p) {
        const float* w0 = We2 + (8 * q + 2 * p) * D_EMBED;
        const float* w1 = w0 + D_EMBED;
        const float h0 = hid[p].x, h1 = hid[p].y;
#pragma unroll
        for (int kk = 0; kk < D_EMBED; ++kk)
            o[kk] = fmaf(h0, w0[kk], fmaf(h1, w1[kk], o[kk]));
    }
#pragma unroll
    for (int kk = 0; kk < D_EMBED; ++kk) o[kk] += __shfl_xor(o[kk], 1, 64);
#pragma unroll
    for (int kk = 0; kk < D_EMBED; ++kk) o[kk] += __shfl_xor(o[kk], 2, 64);

    // ---- quarter-select o[4q..4q+4) via cndmask (NO dynamic reg indexing)
    float4 v;
    {
        float s0, s1;
        s0 = (q & 1) ? o[4]  : o[0];  s1 = (q & 1) ? o[12] : o[8];
        v.x = (q & 2) ? s1 : s0;
        s0 = (q & 1) ? o[5]  : o[1];  s1 = (q & 1) ? o[13] : o[9];
        v.y = (q & 2) ? s1 : s0;
        s0 = (q & 1) ? o[6]  : o[2];  s1 = (q & 1) ? o[14] : o[10];
        v.z = (q & 2) ? s1 : s0;
        s0 = (q & 1) ? o[7]  : o[3];  s1 = (q & 1) ? o[15] : o[11];
        v.w = (q & 2) ? s1 : s0;
    }
    ((float4*)(out + slot * D_EMBED))[q] = v;
}

// ---------------------------------------------------------------------------
extern "C" void kernel_launch(void* const* d_in, const int* in_sizes, int n_in,
                              void* d_out, int out_size, void* d_ws, size_t ws_size,
                              hipStream_t stream) {
    const float* h_from_x = (const float*)d_in[0];
    const float* h_from_z = (const float*)d_in[1];
    const float* h_to     = (const float*)d_in[2];
    const int*   syn_x    = (const int*)d_in[3];
    const int*   syn_z    = (const int*)d_in[4];
    const int*   fi_x     = (const int*)d_in[5];
    const int*   ti_x     = (const int*)d_in[6];
    const int*   fi_z     = (const int*)d_in[7];
    const int*   ti_z     = (const int*)d_in[8];
    const float* Wx1      = (const float*)d_in[9];
    const float* Wx2      = (const float*)d_in[10];
    const float* Wz1      = (const float*)d_in[11];
    const float* Wz2      = (const float*)d_in[12];
    const float* We1      = (const float*)d_in[13];
    const float* We2      = (const float*)d_in[14];

    int* ws = (int*)d_ws;
    int* ids_x  = ws + WS_IDS_X;
    int* ids_z  = ws + WS_IDS_Z;
    int* off_x  = ws + WS_OFF_X;
    int* off_z  = ws + WS_OFF_Z;
    int* cnt_x  = ws + WS_CNT_X;
    int* cnt_z  = ws + WS_CNT_Z;
    int* cur_x  = ws + WS_CUR_X;
    int* cur_z  = ws + WS_CUR_Z;
    int* incl_x = ws + WS_INCL_X;
    int* incl_z = ws + WS_INCL_Z;
    int* psum   = ws + WS_PSUM;
    int* base   = ws + WS_BASE;
    uint4* a1x  = (uint4*)(ws + WS_A1X);
    uint4* a1z  = (uint4*)(ws + WS_A1Z);

    // cur_* are dead after fill -> reuse as syndrome bitmasks
    unsigned* bits_x = (unsigned*)cur_x;
    unsigned* bits_z = (unsigned*)cur_z;

    hipMemsetAsync(cnt_x, 0, 2 * NUM_VN * sizeof(int), stream);

    hist_kernel<<<dim3((NUM_E + 255) / 256), dim3(256), 0, stream>>>(
        ti_x, ti_z, cnt_x, cnt_z);
    scan1_kernel<<<dim3(SCAN_CHUNKS, 2), dim3(1024), 0, stream>>>(
        cnt_x, cnt_z, incl_x, incl_z, psum);
    scan2_kernel<<<dim3(1), dim3(64), 0, stream>>>(psum, base);
    scan3_kernel<<<dim3(SCAN_CHUNKS, 2), dim3(1024), 0, stream>>>(
        cnt_x, cnt_z, incl_x, incl_z, base, off_x, off_z, cur_x, cur_z);
    fill_kernel<<<dim3((NUM_E + 255) / 256), dim3(256), 0, stream>>>(
        ti_x, ti_z, fi_x, fi_z, cur_x, cur_z, ids_x, ids_z);
    pack_bits_kernel<<<dim3((NUM_CN + 255) / 256), dim3(256), 0, stream>>>(
        syn_x, syn_z, bits_x, bits_z);

    a1_kernel<<<dim3((NUM_CN * BATCH + 255) / 256, 2), dim3(256), 0, stream>>>(
        h_from_x, h_from_z, Wx1, Wz1, bits_x, bits_z, a1x, a1z);

    gather_node_kernel<<<dim3((NUM_VN * 64) / 256), dim3(256), 0, stream>>>(
        h_to, off_x, ids_x, off_z, ids_z, a1x, a1z,
        Wx1, Wx2, Wz1, Wz2, We1, We2, (float*)d_out);
}

// Round 5
// 600.106 us; speedup vs baseline: 3.5441x; 1.7795x over previous
//
#include <hip/hip_runtime.h>

#define NUM_CN   25000
#define NUM_VN   50000
#define NUM_E    200000
#define D_EMBED  16
#define D_HIDDEN 32
#define D_MSG    16
#define BATCH    16

// ---------------------------------------------------------------------------
// Workspace layout (int units) — 54.41 MB total (proven available):
#define WS_IDS_X   0           // 200000  (stores FROM node ids, CSR order)
#define WS_IDS_Z   200000      // 200000
#define WS_OFF_X   400000      // 50001
#define WS_OFF_Z   450001      // 50001
#define WS_CNT_X   500002      // 50000
#define WS_CNT_Z   550002      // 50000
#define WS_CUR_X   600002      // 50000
#define WS_CUR_Z   650002      // 50000
#define WS_BITS_X  700002      // 25000 (old incl_x slot; de-aliased from cur)
#define WS_BITS_Z  751202      // 25000 (old incl_z slot)
#define WS_A1X     802816      // 6400000 ints = 25.6 MB bf16
#define WS_A1Z     7202816     // 6400000
#define SCAN_STRIP 49          // 1024 threads x 49 >= 50000

// hist + pack_bits merged: saves a launch; bits no longer alias cur so
// ordering vs fill is free.
__global__ __launch_bounds__(256) void hist_pack_kernel(
    const int* __restrict__ ti_x, const int* __restrict__ ti_z,
    const int* __restrict__ syn_x, const int* __restrict__ syn_z,
    int* __restrict__ cnt_x, int* __restrict__ cnt_z,
    unsigned* __restrict__ bits_x, unsigned* __restrict__ bits_z)
{
    int e = blockIdx.x * 256 + threadIdx.x;
    if (e < NUM_E) {
        atomicAdd(&cnt_x[ti_x[e]], 1);
        atomicAdd(&cnt_z[ti_z[e]], 1);
    }
    if (e < NUM_CN) {
        unsigned wx = 0, wz = 0;
#pragma unroll
        for (int b = 0; b < BATCH; ++b) {
            wx |= (unsigned)(syn_x[b * NUM_CN + e] & 1) << b;
            wz |= (unsigned)(syn_z[b * NUM_CN + e] & 1) << b;
        }
        bits_x[e] = wx;
        bits_z[e] = wz;
    }
}

// single-workgroup-per-channel scan: replaces scan1+scan2+scan3 (3 launches
// -> 1). Thread t serially sums strip [t*49, t*49+49), Hillis-Steele block
// scan of the 1024 partials, then serial prefix write of off/cur.
__global__ __launch_bounds__(1024) void scan_kernel(
    const int* __restrict__ cnt_x, const int* __restrict__ cnt_z,
    int* __restrict__ off_x, int* __restrict__ off_z,
    int* __restrict__ cur_x, int* __restrict__ cur_z)
{
    const int ch = blockIdx.x;
    const int* cnt = ch ? cnt_z : cnt_x;
    int* off = ch ? off_z : off_x;
    int* cur = ch ? cur_z : cur_x;
    const int t  = threadIdx.x;
    const int i0 = t * SCAN_STRIP;

    int s = 0;
#pragma unroll 7
    for (int j = 0; j < SCAN_STRIP; ++j) {
        int i = i0 + j;
        if (i < NUM_VN) s += cnt[i];
    }
    __shared__ int sm[1024];
    sm[t] = s;
    __syncthreads();
    for (int d = 1; d < 1024; d <<= 1) {
        int x = 0;
        if (t >= d) x = sm[t - d];
        __syncthreads();
        if (t >= d) sm[t] += x;
        __syncthreads();
    }
    int run = (t == 0) ? 0 : sm[t - 1];
#pragma unroll 7
    for (int j = 0; j < SCAN_STRIP; ++j) {
        int i = i0 + j;
        if (i < NUM_VN) {
            int c = cnt[i];
            run += c;
            off[i + 1] = run;
            cur[i]     = run - c;
        }
    }
    if (t == 0) off[0] = 0;
}

// fill: CSR slot stores the FROM node id directly.
__global__ __launch_bounds__(256) void fill_kernel(
    const int* __restrict__ ti_x, const int* __restrict__ ti_z,
    const int* __restrict__ fi_x, const int* __restrict__ fi_z,
    int* __restrict__ cur_x, int* __restrict__ cur_z,
    int* __restrict__ ids_x, int* __restrict__ ids_z)
{
    int e = blockIdx.x * 256 + threadIdx.x;
    if (e >= NUM_E) return;
    int px = atomicAdd(&cur_x[ti_x[e]], 1);
    ids_x[px] = fi_x[e];
    int pz = atomicAdd(&cur_z[ti_z[e]], 1);
    ids_z[pz] = fi_z[e];
}

// ---------------------------------------------------------------------------
__device__ __forceinline__ unsigned pack_bf16(float a, float b) {
    unsigned ua = __float_as_uint(a); ua += 0x7fff + ((ua >> 16) & 1);
    unsigned ub = __float_as_uint(b); ub += 0x7fff + ((ub >> 16) & 1);
    return (ua >> 16) | (ub & 0xffff0000u);
}

// a1[ch][cn][b][32] = h_from[b,cn,:] @ W1[0:16,:]  bf16 lane-interleaved:
// per-cn block of 64 uint4; lane b's p-th uint4 at block + p*16 + b.
// MASK FOLDED IN: syn==0 rows are written as bf16 -inf so the gather-side
// relu(a1 + a2) == 0 reproduces mask*relu(...) with no per-edge mask load.
__global__ __launch_bounds__(256) void a1_kernel(
    const float* __restrict__ h_from_x, const float* __restrict__ h_from_z,
    const float* __restrict__ Wx1, const float* __restrict__ Wz1,
    const unsigned* __restrict__ bits_x, const unsigned* __restrict__ bits_z,
    uint4* __restrict__ a1x, uint4* __restrict__ a1z)
{
    int t = blockIdx.x * 256 + threadIdx.x;
    if (t >= NUM_CN * BATCH) return;
    const int ch = blockIdx.y;
    const int b  = t & 15;
    const int cn = t >> 4;
    const float* hsrc = (ch ? h_from_z : h_from_x) + ((size_t)b * NUM_CN + cn) * D_EMBED;
    const float* W1   = ch ? Wz1 : Wx1;
    const unsigned mw = (ch ? bits_z : bits_x)[cn];
    const bool on = (mw >> b) & 1u;
    uint4* dst = (ch ? a1z : a1x) + (size_t)cn * 64;

    float hf[D_EMBED];
#pragma unroll
    for (int i = 0; i < 4; ++i) {
        float4 v = ((const float4*)hsrc)[i];
        hf[4 * i + 0] = v.x; hf[4 * i + 1] = v.y;
        hf[4 * i + 2] = v.z; hf[4 * i + 3] = v.w;
    }
    float a[D_HIDDEN];
#pragma unroll
    for (int j = 0; j < D_HIDDEN; ++j) a[j] = 0.0f;
#pragma unroll
    for (int i = 0; i < D_EMBED; ++i) {
        const float fi = hf[i];
#pragma unroll
        for (int j = 0; j < D_HIDDEN; ++j)
            a[j] = fmaf(fi, W1[i * D_HIDDEN + j], a[j]);
    }
    unsigned u[16];
#pragma unroll
    for (int j = 0; j < 16; ++j)
        u[j] = on ? pack_bf16(a[2 * j], a[2 * j + 1]) : 0xFF80FF80u;
#pragma unroll
    for (int p = 0; p < 4; ++p) {
        uint4 q;
        q.x = u[4 * p + 0]; q.y = u[4 * p + 1];
        q.z = u[4 * p + 2]; q.w = u[4 * p + 3];
        dst[p * 16 + b] = q;
    }
}

// ---------------------------------------------------------------------------
// PROVEN-BEST gather structure (baseline 155us @ VALU 60%): thread=(n,b),
// both channels, bf16 um staging to d_out, separate node kernel. Only change
// vs baseline: -inf mask fold removes the per-edge bits load + mask FMA.
// R0-R3 lessons encoded: no min-wave pin (spills/LDS-demotion), no fusion
// (occupancy drop outweighs 150MB round-trip), no quarter-split (4x waves
// at unchanged per-wave latency).
__device__ __forceinline__ void channel_accum(
    const float* __restrict__ h_to_slot, int n, int b,
    const int* __restrict__ off, const int* __restrict__ ids,
    const uint4* __restrict__ a1,
    const float* __restrict__ W1, const float* __restrict__ W2,
    unsigned* __restrict__ um)
{
    float ht[D_EMBED];
#pragma unroll
    for (int i = 0; i < 4; ++i) {
        float4 v = ((const float4*)h_to_slot)[i];
        ht[4 * i + 0] = v.x; ht[4 * i + 1] = v.y;
        ht[4 * i + 2] = v.z; ht[4 * i + 3] = v.w;
    }
    float2 act[16];
#pragma unroll
    for (int p = 0; p < 16; ++p) { act[p].x = 0.0f; act[p].y = 0.0f; }
#pragma unroll
    for (int i = 0; i < D_EMBED; ++i) {
        const float hi = ht[i];
        const float* w = W1 + (D_EMBED + i) * D_HIDDEN;
#pragma unroll
        for (int p = 0; p < 16; ++p) {
            act[p].x = fmaf(hi, w[2 * p],     act[p].x);
            act[p].y = fmaf(hi, w[2 * p + 1], act[p].y);
        }
    }

    float2 hacc[16];
#pragma unroll
    for (int p = 0; p < 16; ++p) { hacc[p].x = 0.0f; hacc[p].y = 0.0f; }

    const int ks = off[n], ke = off[n + 1];
    int k = ks;
    for (; k + 1 < ke; k += 2) {
        const uint4* pa = a1 + (size_t)ids[k]     * 64 + b;
        const uint4* pb = a1 + (size_t)ids[k + 1] * 64 + b;
        uint4 qa0 = pa[0], qa1 = pa[16], qa2 = pa[32], qa3 = pa[48];
        uint4 qb0 = pb[0], qb1 = pb[16], qb2 = pb[32], qb3 = pb[48];
        unsigned ua[16] = {qa0.x, qa0.y, qa0.z, qa0.w,
                           qa1.x, qa1.y, qa1.z, qa1.w,
                           qa2.x, qa2.y, qa2.z, qa2.w,
                           qa3.x, qa3.y, qa3.z, qa3.w};
#pragma unroll
        for (int p = 0; p < 16; ++p) {
            float lo = __uint_as_float(ua[p] << 16);
            float hi = __uint_as_float(ua[p] & 0xffff0000u);
            hacc[p].x += fmaxf(act[p].x + lo, 0.0f);
            hacc[p].y += fmaxf(act[p].y + hi, 0.0f);
        }
        unsigned ub[16] = {qb0.x, qb0.y, qb0.z, qb0.w,
                           qb1.x, qb1.y, qb1.z, qb1.w,
                           qb2.x, qb2.y, qb2.z, qb2.w,
                           qb3.x, qb3.y, qb3.z, qb3.w};
#pragma unroll
        for (int p = 0; p < 16; ++p) {
            float lo = __uint_as_float(ub[p] << 16);
            float hi = __uint_as_float(ub[p] & 0xffff0000u);
            hacc[p].x += fmaxf(act[p].x + lo, 0.0f);
            hacc[p].y += fmaxf(act[p].y + hi, 0.0f);
        }
    }
    if (k < ke) {
        const uint4* pa = a1 + (size_t)ids[k] * 64 + b;
        uint4 q0 = pa[0], q1 = pa[16], q2 = pa[32], q3 = pa[48];
        unsigned uu[16] = {q0.x, q0.y, q0.z, q0.w,
                           q1.x, q1.y, q1.z, q1.w,
                           q2.x, q2.y, q2.z, q2.w,
                           q3.x, q3.y, q3.z, q3.w};
#pragma unroll
        for (int p = 0; p < 16; ++p) {
            float lo = __uint_as_float(uu[p] << 16);
            float hi = __uint_as_float(uu[p] & 0xffff0000u);
            hacc[p].x += fmaxf(act[p].x + lo, 0.0f);
            hacc[p].y += fmaxf(act[p].y + hi, 0.0f);
        }
    }

    float m[D_MSG];
#pragma unroll
    for (int j = 0; j < D_MSG; ++j) m[j] = 0.0f;
#pragma unroll
    for (int p = 0; p < 16; ++p) {
        const float h0 = hacc[p].x, h1 = hacc[p].y;
        const float* w0 = W2 + (2 * p) * D_MSG;
        const float* w1 = W2 + (2 * p + 1) * D_MSG;
#pragma unroll
        for (int j = 0; j < D_MSG; ++j)
            m[j] = fmaf(h0, w0[j], fmaf(h1, w1[j], m[j]));
    }
#pragma unroll
    for (int j = 0; j < 8; ++j) um[j] = pack_bf16(m[2 * j], m[2 * j + 1]);
}

__global__ __launch_bounds__(256) void gather_kernel(
    const float* __restrict__ h_to,
    const int* __restrict__ off_x, const int* __restrict__ ids_x,
    const int* __restrict__ off_z, const int* __restrict__ ids_z,
    const uint4* __restrict__ a1x, const uint4* __restrict__ a1z,
    const float* __restrict__ Wx1, const float* __restrict__ Wx2,
    const float* __restrict__ Wz1, const float* __restrict__ Wz2,
    uint4* __restrict__ out_m)
{
    const int t = blockIdx.x * 256 + threadIdx.x;
    if (t >= NUM_VN * BATCH) return;
    const int b = t & (BATCH - 1);
    const int n = t >> 4;
    const size_t slot = (size_t)b * NUM_VN + n;
    const float* ht_slot = h_to + slot * D_EMBED;

    unsigned um[16];
    channel_accum(ht_slot, n, b, off_x, ids_x, a1x, Wx1, Wx2, um);
    channel_accum(ht_slot, n, b, off_z, ids_z, a1z, Wz1, Wz2, um + 8);

    uint4* dst = out_m + slot * 4;
#pragma unroll
    for (int p = 0; p < 4; ++p) {
        uint4 q;
        q.x = um[4 * p + 0]; q.y = um[4 * p + 1];
        q.z = um[4 * p + 2]; q.w = um[4 * p + 3];
        dst[p] = q;
    }
}

// node MLP: reads its own slot {mx|mz} + h_to, computes 48->32(relu)->16,
// overwrites the slot with the final fp32 output (same thread owns both).
__global__ __launch_bounds__(256) void node_kernel(
    const float* __restrict__ h_to,
    const float* __restrict__ We1, const float* __restrict__ We2,
    float* out)
{
    const int t = blockIdx.x * 256 + threadIdx.x;
    if (t >= NUM_VN * BATCH) return;
    const int b = t & (BATCH - 1);
    const int n = t >> 4;
    const size_t slot = (size_t)b * NUM_VN + n;

    const uint4* pm = (const uint4*)out + slot * 4;
    uint4 q0 = pm[0], q1 = pm[1], q2 = pm[2], q3 = pm[3];
    unsigned uu[16] = {q0.x, q0.y, q0.z, q0.w,
                       q1.x, q1.y, q1.z, q1.w,
                       q2.x, q2.y, q2.z, q2.w,
                       q3.x, q3.y, q3.z, q3.w};
    float f[48];
#pragma unroll
    for (int p = 0; p < 16; ++p) {
        f[2 * p]     = __uint_as_float(uu[p] << 16);
        f[2 * p + 1] = __uint_as_float(uu[p] & 0xffff0000u);
    }
#pragma unroll
    for (int i = 0; i < 4; ++i) {
        float4 v = ((const float4*)(h_to + slot * D_EMBED))[i];
        f[32 + 4 * i + 0] = v.x; f[32 + 4 * i + 1] = v.y;
        f[32 + 4 * i + 2] = v.z; f[32 + 4 * i + 3] = v.w;
    }

    float2 hid[16];
#pragma unroll
    for (int p = 0; p < 16; ++p) { hid[p].x = 0.0f; hid[p].y = 0.0f; }
#pragma unroll
    for (int i = 0; i < 48; ++i) {
        const float fi = f[i];
        const float* w = We1 + i * D_HIDDEN;
#pragma unroll
        for (int p = 0; p < 16; ++p) {
            hid[p].x = fmaf(fi, w[2 * p],     hid[p].x);
            hid[p].y = fmaf(fi, w[2 * p + 1], hid[p].y);
        }
    }
#pragma unroll
    for (int p = 0; p < 16; ++p) {
        hid[p].x = fmaxf(hid[p].x, 0.0f);
        hid[p].y = fmaxf(hid[p].y, 0.0f);
    }

    float o[D_EMBED];
#pragma unroll
    for (int k = 0; k < D_EMBED; ++k) o[k] = 0.0f;
#pragma unroll
    for (int p = 0; p < 16; ++p) {
        const float h0 = hid[p].x, h1 = hid[p].y;
        const float* w0 = We2 + (2 * p) * D_EMBED;
        const float* w1 = We2 + (2 * p + 1) * D_EMBED;
#pragma unroll
        for (int k = 0; k < D_EMBED; ++k)
            o[k] = fmaf(h0, w0[k], fmaf(h1, w1[k], o[k]));
    }

#pragma unroll
    for (int i = 0; i < 4; ++i) {
        float4 v;
        v.x = o[4 * i + 0]; v.y = o[4 * i + 1];
        v.z = o[4 * i + 2]; v.w = o[4 * i + 3];
        ((float4*)(out + slot * D_EMBED))[i] = v;
    }
}

// ---------------------------------------------------------------------------
extern "C" void kernel_launch(void* const* d_in, const int* in_sizes, int n_in,
                              void* d_out, int out_size, void* d_ws, size_t ws_size,
                              hipStream_t stream) {
    const float* h_from_x = (const float*)d_in[0];
    const float* h_from_z = (const float*)d_in[1];
    const float* h_to     = (const float*)d_in[2];
    const int*   syn_x    = (const int*)d_in[3];
    const int*   syn_z    = (const int*)d_in[4];
    const int*   fi_x     = (const int*)d_in[5];
    const int*   ti_x     = (const int*)d_in[6];
    const int*   fi_z     = (const int*)d_in[7];
    const int*   ti_z     = (const int*)d_in[8];
    const float* Wx1      = (const float*)d_in[9];
    const float* Wx2      = (const float*)d_in[10];
    const float* Wz1      = (const float*)d_in[11];
    const float* Wz2      = (const float*)d_in[12];
    const float* We1      = (const float*)d_in[13];
    const float* We2      = (const float*)d_in[14];

    int* ws = (int*)d_ws;
    int* ids_x  = ws + WS_IDS_X;
    int* ids_z  = ws + WS_IDS_Z;
    int* off_x  = ws + WS_OFF_X;
    int* off_z  = ws + WS_OFF_Z;
    int* cnt_x  = ws + WS_CNT_X;
    int* cnt_z  = ws + WS_CNT_Z;
    int* cur_x  = ws + WS_CUR_X;
    int* cur_z  = ws + WS_CUR_Z;
    unsigned* bits_x = (unsigned*)(ws + WS_BITS_X);
    unsigned* bits_z = (unsigned*)(ws + WS_BITS_Z);
    uint4* a1x  = (uint4*)(ws + WS_A1X);
    uint4* a1z  = (uint4*)(ws + WS_A1Z);

    hipMemsetAsync(cnt_x, 0, 2 * NUM_VN * sizeof(int), stream);

    hist_pack_kernel<<<dim3((NUM_E + 255) / 256), dim3(256), 0, stream>>>(
        ti_x, ti_z, syn_x, syn_z, cnt_x, cnt_z, bits_x, bits_z);
    scan_kernel<<<dim3(2), dim3(1024), 0, stream>>>(
        cnt_x, cnt_z, off_x, off_z, cur_x, cur_z);
    fill_kernel<<<dim3((NUM_E + 255) / 256), dim3(256), 0, stream>>>(
        ti_x, ti_z, fi_x, fi_z, cur_x, cur_z, ids_x, ids_z);

    a1_kernel<<<dim3((NUM_CN * BATCH + 255) / 256, 2), dim3(256), 0, stream>>>(
        h_from_x, h_from_z, Wx1, Wz1, bits_x, bits_z, a1x, a1z);

    gather_kernel<<<dim3((NUM_VN * BATCH) / 256), dim3(256), 0, stream>>>(
        h_to, off_x, ids_x, off_z, ids_z, a1x, a1z,
        Wx1, Wx2, Wz1, Wz2, (uint4*)d_out);

    node_kernel<<<dim3((NUM_VN * BATCH) / 256), dim3(256), 0, stream>>>(
        h_to, We1, We2, (float*)d_out);
}